// Round 1
// baseline (203.446 us; speedup 1.0000x reference)
//
#include <hip/hip_runtime.h>
#include <stdint.h>

// DiffAttention: O[n,h,d] = sum_l sigmoid(q_n.k_l) v_l / sum_l sigmoid(q_n.k_l)
// N=L=4096, H=8, M=D=64, fp32 in/out, bf16 MFMA compute.
//
// Per block: head h = bid&7 (XCD-L2 locality), 128 q-rows, 4 waves x 32 rows.
// Scores computed TRANSPOSED (A=K, B=Q) so C/D col = q-row = lane&31, which
// matches the PV A-operand lane axis; C/D->A fixup is one shfl_xor(32).

typedef __bf16 bf16x8 __attribute__((ext_vector_type(8)));
typedef float  f32x16 __attribute__((ext_vector_type(16)));

constexpr int NH = 8, MD = 64, NL = 4096;
constexpr int KSTR = 72;  // ushort stride: 144B rows -> 16B aligned, conflict-free

__device__ __forceinline__ unsigned pack2(float a, float b) {
  unsigned short ua = __builtin_bit_cast(unsigned short, (__bf16)a);
  unsigned short ub = __builtin_bit_cast(unsigned short, (__bf16)b);
  return (unsigned)ua | ((unsigned)ub << 16);
}

__global__ __launch_bounds__(256, 2) void diffattn_kernel(
    const float* __restrict__ Qg, const float* __restrict__ Kg,
    const float* __restrict__ Vg, float* __restrict__ Og) {
  __shared__ unsigned short Ksh[64 * KSTR];   // [l][k] bf16
  __shared__ unsigned short Vtsh[64 * KSTR];  // [d][l] bf16 (transposed)
  __shared__ float Zsh[4][32];

  const int tid  = threadIdx.x;
  const int w    = tid >> 6;
  const int lane = tid & 63;
  const int col  = lane & 31;
  const int hi   = lane >> 5;

  const int h  = blockIdx.x & 7;
  const int n0 = (blockIdx.x >> 3) * 128;

  // Q fragments (B operand): B[k][n=q-row], lane: n=col, k = kc*16 + hi*8 + j
  bf16x8 qf[4];
  {
    const float* qp = Qg + ((n0 + w * 32 + col) * NH + h) * MD;
#pragma unroll
    for (int kc = 0; kc < 4; ++kc) {
      const float4 x = *(const float4*)(qp + kc * 16 + hi * 8);
      const float4 y = *(const float4*)(qp + kc * 16 + hi * 8 + 4);
      bf16x8 f;
      f[0] = (__bf16)x.x; f[1] = (__bf16)x.y; f[2] = (__bf16)x.z; f[3] = (__bf16)x.w;
      f[4] = (__bf16)y.x; f[5] = (__bf16)y.y; f[6] = (__bf16)y.z; f[7] = (__bf16)y.w;
      qf[kc] = f;
    }
  }

  f32x16 oacc[2];
#pragma unroll
  for (int i = 0; i < 16; ++i) { oacc[0][i] = 0.f; oacc[1][i] = 0.f; }
  float zacc = 0.f;

  for (int l0 = 0; l0 < NL; l0 += 64) {
    __syncthreads();
    // ---- stage K tile [64 l][64 k] fp32 -> bf16, coalesced reads, b64 stores
#pragma unroll
    for (int i = 0; i < 4; ++i) {
      const int f4 = tid + i * 256;
      const int lr = f4 >> 4, c4 = f4 & 15;
      const float4 v = *(const float4*)(Kg + ((l0 + lr) * NH + h) * MD + c4 * 4);
      unsigned* dst = (unsigned*)&Ksh[lr * KSTR + c4 * 4];
      dst[0] = pack2(v.x, v.y);
      dst[1] = pack2(v.z, v.w);
    }
    // ---- stage V tile transposed: Vtsh[d][l]; lane==l so LDS writes are
    // 2B-stride conflict-free; each thread's 4 float4 = one 64B line
    {
      const int lr = tid & 63, dbase = (tid >> 6) * 16;
      const float* vp = Vg + ((l0 + lr) * NH + h) * MD + dbase;
#pragma unroll
      for (int i = 0; i < 4; ++i) {
        const float4 v = *(const float4*)(vp + i * 4);
        const int d0 = dbase + i * 4;
        Vtsh[(d0 + 0) * KSTR + lr] = __builtin_bit_cast(unsigned short, (__bf16)v.x);
        Vtsh[(d0 + 1) * KSTR + lr] = __builtin_bit_cast(unsigned short, (__bf16)v.y);
        Vtsh[(d0 + 2) * KSTR + lr] = __builtin_bit_cast(unsigned short, (__bf16)v.z);
        Vtsh[(d0 + 3) * KSTR + lr] = __builtin_bit_cast(unsigned short, (__bf16)v.w);
      }
    }
    __syncthreads();

    // ---- scores^T: D1[lh] (32 l x 32 m) = K(32l x 64k) x Q(64k x 32m)
    f32x16 d1[2];
#pragma unroll
    for (int i = 0; i < 16; ++i) { d1[0][i] = 0.f; d1[1][i] = 0.f; }
#pragma unroll
    for (int lh = 0; lh < 2; ++lh) {
      const unsigned short* kp = &Ksh[(lh * 32 + col) * KSTR + hi * 8];
#pragma unroll
      for (int kc = 0; kc < 4; ++kc) {
        const bf16x8 kf = *(const bf16x8*)(kp + kc * 16);
        d1[lh] = __builtin_amdgcn_mfma_f32_32x32x16_bf16(kf, qf[kc], d1[lh], 0, 0, 0);
      }
    }

    // ---- sigmoid + Z accumulate + pack pairs (consecutive l_local) to bf16
    unsigned pk[2][8];
#pragma unroll
    for (int lh = 0; lh < 2; ++lh) {
      float s[16];
#pragma unroll
      for (int r = 0; r < 16; ++r) {
        const float e = __builtin_amdgcn_exp2f(d1[lh][r] * -1.44269504088896340736f);
        s[r] = __builtin_amdgcn_rcpf(1.0f + e);
        zacc += s[r];
      }
#pragma unroll
      for (int p = 0; p < 8; ++p) pk[lh][p] = pack2(s[2 * p], s[2 * p + 1]);
    }

    // ---- O += P(32m x 64l) x V(64l x 64d); P A-frag built via lane^32 swap
#pragma unroll
    for (int kc2 = 0; kc2 < 4; ++kc2) {
      const int lh = kc2 >> 1, s4 = (kc2 & 1) * 4;
      const unsigned send0 = hi ? pk[lh][s4 + 0] : pk[lh][s4 + 2];
      const unsigned send1 = hi ? pk[lh][s4 + 1] : pk[lh][s4 + 3];
      const unsigned recv0 = (unsigned)__shfl_xor((int)send0, 32, 64);
      const unsigned recv1 = (unsigned)__shfl_xor((int)send1, 32, 64);
      union { unsigned u[4]; bf16x8 v; } pf;
      if (hi == 0) {
        pf.u[0] = pk[lh][s4 + 0]; pf.u[1] = pk[lh][s4 + 1];
        pf.u[2] = recv0;          pf.u[3] = recv1;
      } else {
        pf.u[0] = recv0;          pf.u[1] = recv1;
        pf.u[2] = pk[lh][s4 + 2]; pf.u[3] = pk[lh][s4 + 3];
      }
#pragma unroll
      for (int ds = 0; ds < 2; ++ds) {
        const bf16x8 vf =
            *(const bf16x8*)(&Vtsh[(ds * 32 + col) * KSTR + kc2 * 16 + hi * 8]);
        oacc[ds] = __builtin_amdgcn_mfma_f32_32x32x16_bf16(pf.v, vf, oacc[ds], 0, 0, 0);
      }
    }
  }

  // ---- epilogue: Z = lane + lane^32 partial, broadcast via LDS, divide, store
  const float zrow = zacc + __shfl_xor(zacc, 32, 64);
  if (hi == 0) Zsh[w][col] = zrow;
  __syncthreads();

  float zi[4][4];
#pragma unroll
  for (int t = 0; t < 4; ++t) {
    const float4 zz = *(const float4*)&Zsh[w][8 * t + 4 * hi];
    zi[t][0] = __builtin_amdgcn_rcpf(zz.x);
    zi[t][1] = __builtin_amdgcn_rcpf(zz.y);
    zi[t][2] = __builtin_amdgcn_rcpf(zz.z);
    zi[t][3] = __builtin_amdgcn_rcpf(zz.w);
  }

#pragma unroll
  for (int ds = 0; ds < 2; ++ds) {
    const int d = ds * 32 + col;
#pragma unroll
    for (int r = 0; r < 16; ++r) {
      const int row = (r & 3) + 8 * (r >> 2) + 4 * hi;
      Og[((n0 + w * 32 + row) * NH + h) * MD + d] = oacc[ds][r] * zi[r >> 2][r & 3];
    }
  }
}

extern "C" void kernel_launch(void* const* d_in, const int* in_sizes, int n_in,
                              void* d_out, int out_size, void* d_ws, size_t ws_size,
                              hipStream_t stream) {
  const float* Q = (const float*)d_in[0];
  const float* K = (const float*)d_in[1];
  const float* V = (const float*)d_in[2];
  float* O = (float*)d_out;
  // 8 heads x 32 q-tiles of 128 rows = 256 blocks; h = bid&7 for XCD locality
  diffattn_kernel<<<dim3(256), dim3(256), 0, stream>>>(Q, K, V, O);
}

// Round 2
// 144.940 us; speedup vs baseline: 1.4037x; 1.4037x over previous
//
#include <hip/hip_runtime.h>
#include <stdint.h>

// DiffAttention: O[n,h,d] = sum_l sigmoid(q_n.k_l) v_l / sum_l sigmoid(q_n.k_l)
// N=L=4096, H=8, M=D=64, fp32 in/out, bf16 MFMA compute.
//
// R2: split-L for occupancy. Partial kernel: grid = 8 heads x 32 n-tiles x
// NSPLIT l-chunks; each block = 128 q-rows x (4096/NSPLIT) l, writes raw
// numerator + Z to d_ws. Combine kernel sums partials and divides.
// Sigmoid's -log2e prescale is folded into the Q fragments.

typedef __bf16 bf16x8 __attribute__((ext_vector_type(8)));
typedef float  f32x16 __attribute__((ext_vector_type(16)));

constexpr int NH = 8, MD = 64, NL = 4096, NN = 4096;
constexpr int KSTR = 72;  // ushort stride: 144B rows -> 16B aligned, conflict-free
constexpr size_t ONUM_ELEMS = (size_t)NN * NH * MD;  // per split
constexpr size_t Z_ELEMS    = (size_t)NN * NH;       // per split

__device__ __forceinline__ unsigned pack2(float a, float b) {
  unsigned short ua = __builtin_bit_cast(unsigned short, (__bf16)a);
  unsigned short ub = __builtin_bit_cast(unsigned short, (__bf16)b);
  return (unsigned)ua | ((unsigned)ub << 16);
}

__global__ __launch_bounds__(256, 4) void diffattn_partial(
    const float* __restrict__ Qg, const float* __restrict__ Kg,
    const float* __restrict__ Vg, float* __restrict__ Onum,
    float* __restrict__ Zp, int nsplit, int lLen) {
  __shared__ unsigned short Ksh[64 * KSTR];   // [l][k] bf16
  __shared__ unsigned short Vtsh[64 * KSTR];  // [d][l] bf16 (transposed)

  const int tid  = threadIdx.x;
  const int w    = tid >> 6;
  const int lane = tid & 63;
  const int col  = lane & 31;
  const int hi   = lane >> 5;

  const int h     = blockIdx.x & 7;
  const int tmp   = blockIdx.x >> 3;
  const int split = tmp % nsplit;
  const int n0    = (tmp / nsplit) * 128;
  const int lBeg  = split * lLen;

  // Q fragments (B operand), prescaled by -log2e so MFMA result feeds exp2
  // directly: d1 = -log2e * (q.k); sigmoid = rcp(1 + exp2(d1)).
  bf16x8 qf[4];
  {
    const float* qp = Qg + ((n0 + w * 32 + col) * NH + h) * MD;
    const float c = -1.4426950408889634f;
#pragma unroll
    for (int kc = 0; kc < 4; ++kc) {
      const float4 x = *(const float4*)(qp + kc * 16 + hi * 8);
      const float4 y = *(const float4*)(qp + kc * 16 + hi * 8 + 4);
      bf16x8 f;
      f[0] = (__bf16)(c * x.x); f[1] = (__bf16)(c * x.y);
      f[2] = (__bf16)(c * x.z); f[3] = (__bf16)(c * x.w);
      f[4] = (__bf16)(c * y.x); f[5] = (__bf16)(c * y.y);
      f[6] = (__bf16)(c * y.z); f[7] = (__bf16)(c * y.w);
      qf[kc] = f;
    }
  }

  f32x16 oacc[2];
#pragma unroll
  for (int i = 0; i < 16; ++i) { oacc[0][i] = 0.f; oacc[1][i] = 0.f; }
  float zacc = 0.f;

  for (int l0 = lBeg; l0 < lBeg + lLen; l0 += 64) {
    __syncthreads();
    // ---- stage K tile [64 l][64 k] fp32 -> bf16, coalesced reads
#pragma unroll
    for (int i = 0; i < 4; ++i) {
      const int f4 = tid + i * 256;
      const int lr = f4 >> 4, c4 = f4 & 15;
      const float4 v = *(const float4*)(Kg + ((l0 + lr) * NH + h) * MD + c4 * 4);
      unsigned* dst = (unsigned*)&Ksh[lr * KSTR + c4 * 4];
      dst[0] = pack2(v.x, v.y);
      dst[1] = pack2(v.z, v.w);
    }
    // ---- stage V tile transposed: Vtsh[d][l]; lane==l -> 2B-stride writes
    {
      const int lr = tid & 63, dbase = (tid >> 6) * 16;
      const float* vp = Vg + ((l0 + lr) * NH + h) * MD + dbase;
#pragma unroll
      for (int i = 0; i < 4; ++i) {
        const float4 v = *(const float4*)(vp + i * 4);
        const int d0 = dbase + i * 4;
        Vtsh[(d0 + 0) * KSTR + lr] = __builtin_bit_cast(unsigned short, (__bf16)v.x);
        Vtsh[(d0 + 1) * KSTR + lr] = __builtin_bit_cast(unsigned short, (__bf16)v.y);
        Vtsh[(d0 + 2) * KSTR + lr] = __builtin_bit_cast(unsigned short, (__bf16)v.z);
        Vtsh[(d0 + 3) * KSTR + lr] = __builtin_bit_cast(unsigned short, (__bf16)v.w);
      }
    }
    __syncthreads();

    // ---- scores^T: D1[lh] (32 l x 32 m) = K(32l x 64k) x Qscaled(64k x 32m)
    f32x16 d1[2];
#pragma unroll
    for (int i = 0; i < 16; ++i) { d1[0][i] = 0.f; d1[1][i] = 0.f; }
#pragma unroll
    for (int lh = 0; lh < 2; ++lh) {
      const unsigned short* kp = &Ksh[(lh * 32 + col) * KSTR + hi * 8];
#pragma unroll
      for (int kc = 0; kc < 4; ++kc) {
        const bf16x8 kf = *(const bf16x8*)(kp + kc * 16);
        d1[lh] = __builtin_amdgcn_mfma_f32_32x32x16_bf16(kf, qf[kc], d1[lh], 0, 0, 0);
      }
    }

    // ---- sigmoid + Z accumulate + pack pairs (consecutive l_local) to bf16
    unsigned pk[2][8];
#pragma unroll
    for (int lh = 0; lh < 2; ++lh) {
      float s[16];
#pragma unroll
      for (int r = 0; r < 16; ++r) {
        const float e = __builtin_amdgcn_exp2f(d1[lh][r]);
        s[r] = __builtin_amdgcn_rcpf(1.0f + e);
        zacc += s[r];
      }
#pragma unroll
      for (int p = 0; p < 8; ++p) pk[lh][p] = pack2(s[2 * p], s[2 * p + 1]);
    }

    // ---- O += P(32m x 64l) x V(64l x 64d); P A-frag built via lane^32 swap
#pragma unroll
    for (int kc2 = 0; kc2 < 4; ++kc2) {
      const int lh = kc2 >> 1, s4 = (kc2 & 1) * 4;
      const unsigned send0 = hi ? pk[lh][s4 + 0] : pk[lh][s4 + 2];
      const unsigned send1 = hi ? pk[lh][s4 + 1] : pk[lh][s4 + 3];
      const unsigned recv0 = (unsigned)__shfl_xor((int)send0, 32, 64);
      const unsigned recv1 = (unsigned)__shfl_xor((int)send1, 32, 64);
      union { unsigned u[4]; bf16x8 v; } pf;
      if (hi == 0) {
        pf.u[0] = pk[lh][s4 + 0]; pf.u[1] = pk[lh][s4 + 1];
        pf.u[2] = recv0;          pf.u[3] = recv1;
      } else {
        pf.u[0] = recv0;          pf.u[1] = recv1;
        pf.u[2] = pk[lh][s4 + 2]; pf.u[3] = pk[lh][s4 + 3];
      }
#pragma unroll
      for (int ds = 0; ds < 2; ++ds) {
        const bf16x8 vf =
            *(const bf16x8*)(&Vtsh[(ds * 32 + col) * KSTR + kc2 * 16 + hi * 8]);
        oacc[ds] = __builtin_amdgcn_mfma_f32_32x32x16_bf16(pf.v, vf, oacc[ds], 0, 0, 0);
      }
    }
  }

  // ---- epilogue: store raw numerator + Z partial (no divide here)
  const float zrow = zacc + __shfl_xor(zacc, 32, 64);
  if (hi == 0) Zp[(size_t)split * Z_ELEMS + (n0 + w * 32 + col) * NH + h] = zrow;

  float* onum = Onum + (size_t)split * ONUM_ELEMS;
#pragma unroll
  for (int ds = 0; ds < 2; ++ds) {
    const int d = ds * 32 + col;
#pragma unroll
    for (int r = 0; r < 16; ++r) {
      const int row = (r & 3) + 8 * (r >> 2) + 4 * hi;
      onum[((n0 + w * 32 + row) * NH + h) * MD + d] = oacc[ds][r];
    }
  }
}

__global__ __launch_bounds__(256) void diffattn_combine(
    const float* __restrict__ Onum, const float* __restrict__ Zp,
    float* __restrict__ Og, int nsplit) {
  const int idx = blockIdx.x * 256 + threadIdx.x;  // one float4 of output
  if (idx >= (int)(ONUM_ELEMS / 4)) return;
  const int nh = idx >> 4;
  const int d4 = (idx & 15) * 4;
  float z = 0.f;
  float4 o = make_float4(0.f, 0.f, 0.f, 0.f);
  for (int s = 0; s < nsplit; ++s) {
    z += Zp[(size_t)s * Z_ELEMS + nh];
    const float4 t = *(const float4*)(Onum + (size_t)s * ONUM_ELEMS + nh * MD + d4);
    o.x += t.x; o.y += t.y; o.z += t.z; o.w += t.w;
  }
  const float zi = __builtin_amdgcn_rcpf(z);
  float4 r = make_float4(o.x * zi, o.y * zi, o.z * zi, o.w * zi);
  *(float4*)(Og + (size_t)nh * MD + d4) = r;
}

extern "C" void kernel_launch(void* const* d_in, const int* in_sizes, int n_in,
                              void* d_out, int out_size, void* d_ws, size_t ws_size,
                              hipStream_t stream) {
  const float* Q = (const float*)d_in[0];
  const float* K = (const float*)d_in[1];
  const float* V = (const float*)d_in[2];
  float* O = (float*)d_out;

  // Pick the largest power-of-2 split whose workspace fits (constant per run).
  int nsplit = 4;
  while (nsplit > 1 &&
         (size_t)nsplit * (ONUM_ELEMS + Z_ELEMS) * sizeof(float) > ws_size)
    nsplit >>= 1;

  float* Onum = (float*)d_ws;
  float* Zp   = Onum + (size_t)nsplit * ONUM_ELEMS;

  const int lLen = NL / nsplit;
  diffattn_partial<<<dim3(8 * 32 * nsplit), dim3(256), 0, stream>>>(
      Q, K, V, Onum, Zp, nsplit, lLen);
  diffattn_combine<<<dim3((ONUM_ELEMS / 4 + 255) / 256), dim3(256), 0, stream>>>(
      Onum, Zp, O, nsplit);
}